// Round 10
// baseline (596.207 us; speedup 1.0000x reference)
//
#include <hip/hip_runtime.h>
#include <hip/hip_fp16.h>
#include <math.h>

#define TPB 256
#define CAP 64   // ELL row capacity; in-deg ~ Poisson(16); P(deg>=64) ~ 1e-20; clamped anyway.

typedef _Float16 f16x8 __attribute__((ext_vector_type(8)));
typedef float f32x4 __attribute__((ext_vector_type(4)));

// ---------------- fused count + ELL fill, 4 edges/thread ----------------
// Atomic-throughput-bound at ~22 G atomics/s (measured r4-r9); algorithmic ceiling.
__global__ __launch_bounds__(TPB) void k_count(const int* __restrict__ ei, int E,
                                               int* __restrict__ cnt, int* __restrict__ od,
                                               unsigned short* __restrict__ slots) {
    int t = blockIdx.x * TPB + threadIdx.x;
    int base = t * 4;
    if (base + 3 < E) {
        int4 s4 = *(const int4*)(ei + base);
        int4 d4 = *(const int4*)(ei + E + base);
        int p0 = atomicAdd(&cnt[d4.x], 1);
        int p1 = atomicAdd(&cnt[d4.y], 1);
        int p2 = atomicAdd(&cnt[d4.z], 1);
        int p3 = atomicAdd(&cnt[d4.w], 1);
        atomicAdd(&od[s4.x], 1);
        atomicAdd(&od[s4.y], 1);
        atomicAdd(&od[s4.z], 1);
        atomicAdd(&od[s4.w], 1);
        if (p0 < CAP) slots[(d4.x << 6) + p0] = (unsigned short)s4.x;
        if (p1 < CAP) slots[(d4.y << 6) + p1] = (unsigned short)s4.y;
        if (p2 < CAP) slots[(d4.z << 6) + p2] = (unsigned short)s4.z;
        if (p3 < CAP) slots[(d4.w << 6) + p3] = (unsigned short)s4.w;
    } else {
        for (int e = base; e < E; ++e) {
            int s = ei[e], d = ei[E + e];
            int pos = atomicAdd(&cnt[d], 1);
            if (pos < CAP) slots[(d << 6) + pos] = (unsigned short)s;
            atomicAdd(&od[s], 1);
        }
    }
}

// ---------------- norms ----------------
__global__ __launch_bounds__(TPB) void k_norm(const int* __restrict__ od, const int* __restrict__ cnt,
                                              float* __restrict__ onr, float* __restrict__ inr, int N) {
    int i = blockIdx.x * TPB + threadIdx.x;
    if (i < N) {
        onr[i] = 1.0f / sqrtf(fmaxf((float)od[i], 1.0f));
        inr[i] = 1.0f / sqrtf(fmaxf((float)cnt[i], 1.0f));
    }
}

// ---------------- transpose+convert weights to fp16 WT[j][k] = W[k][j] ----------------
__global__ __launch_bounds__(TPB) void k_cvtw(const float* __restrict__ W1, const float* __restrict__ W2,
                                              const float* __restrict__ Ws, const float* __restrict__ W3,
                                              __half* __restrict__ W1T, __half* __restrict__ W2T,
                                              __half* __restrict__ WCT) {
    int idx = blockIdx.x * TPB + threadIdx.x;   // 0 .. 3*16384-1
    int m = idx >> 14;
    int r = idx & 16383;
    int j = r >> 7, k = r & 127;
    float v;
    __half* dst;
    if (m == 0)      { v = W1[k * 128 + j]; dst = W1T; }
    else if (m == 1) { v = W2[k * 128 + j]; dst = W2T; }
    else             { v = (j < 64) ? Ws[k * 64 + j] : W3[k * 64 + (j - 64)]; dst = WCT; }
    dst[r] = __float2half(v);
}

// ---------------- convert x -> fp16, prescaled by onr[row] ----------------
__global__ __launch_bounds__(TPB) void k_cvt(const float* __restrict__ x, const float* __restrict__ onr,
                                             __half2* __restrict__ xh, int nF4) {  // nF4 = N*32
    int i4 = blockIdx.x * TPB + threadIdx.x;
    if (i4 >= nF4) return;
    int row = i4 >> 5;
    float on = onr[row];
    float4 v = ((const float4*)x)[i4];
    __half2 a = __floats2half2_rn(v.x * on, v.y * on);
    __half2 b = __floats2half2_rn(v.z * on, v.w * on);
    uint2 u;
    u.x = *reinterpret_cast<unsigned int*>(&a);
    u.y = *reinterpret_cast<unsigned int*>(&b);
    ((uint2*)xh)[i4] = u;
}

// ---------------- chunked SpMM pass: 32-feat slice, L2-resident (3.2MB of lines) ----------------
// One wave per dst row; 4 edge-groups x 16 lanes (lane = half2 feat); butterfly reduce.
// Table rows pre-scaled by onr[src]; epilogue applies inr[r]. cb = half2 offset of chunk.
// Streams (slots, aggh) use non-temporal hints to protect the resident table slice.
__global__ __launch_bounds__(TPB) void k_spmmc(const __half2* __restrict__ hp,
                                               const int* __restrict__ cnt,
                                               const unsigned short* __restrict__ slots,
                                               const float* __restrict__ inr,
                                               __half2* __restrict__ aggh, int N, int cb) {
    int l = threadIdx.x & 63;
    int r = blockIdx.x * 4 + (threadIdx.x >> 6);
    if (r >= N) return;
    int n = cnt[r]; if (n > CAP) n = CAP;
    const unsigned short* sl = slots + (r << 6);
    int g = l >> 4;           // edge group 0..3
    int f = l & 15;           // half2 feat within chunk
    float ax = 0.f, ay = 0.f;
    for (int e = 0; e < n; e += 4) {
        int ee = e + g;
        if (ee < n) {
            int src = __builtin_nontemporal_load(sl + ee);
            float2 v = __half22float2(hp[(size_t)src * 64 + cb + f]);
            ax += v.x;  ay += v.y;
        }
    }
    ax += __shfl_xor(ax, 16, 64);  ay += __shfl_xor(ay, 16, 64);
    ax += __shfl_xor(ax, 32, 64);  ay += __shfl_xor(ay, 32, 64);
    if (g == 0) {
        float sc = inr[r];
        __half2 o = __floats2half2_rn(sc * ax, sc * ay);
        unsigned int u = *reinterpret_cast<unsigned int*>(&o);
        __builtin_nontemporal_store(u, (unsigned int*)(aggh + (size_t)r * 64 + cb + f));
    }
}

// ---------------- chunked final pass: gather Ph slice + blend with Pskip slice ----------------
// Ph row stride = 32 half2; Pskip/out row stride = 64 floats. ch = half2 offset (0 or 16).
__global__ __launch_bounds__(TPB) void k_finalc(const float* __restrict__ Pskip,
                                                const __half2* __restrict__ php,
                                                const int* __restrict__ cnt,
                                                const unsigned short* __restrict__ slots,
                                                const float* __restrict__ inr,
                                                const float* __restrict__ b3, const float* __restrict__ bs,
                                                float* __restrict__ out, int N, int ch) {
    int l = threadIdx.x & 63;
    int r = blockIdx.x * 4 + (threadIdx.x >> 6);
    if (r >= N) return;
    int n = cnt[r]; if (n > CAP) n = CAP;
    const unsigned short* sl = slots + (r << 6);
    int g = l >> 4;
    int f = l & 15;
    float ax = 0.f, ay = 0.f;
    for (int e = 0; e < n; e += 4) {
        int ee = e + g;
        if (ee < n) {
            int src = __builtin_nontemporal_load(sl + ee);
            float2 v = __half22float2(php[(size_t)src * 32 + ch + f]);
            ax += v.x;  ay += v.y;
        }
    }
    ax += __shfl_xor(ax, 16, 64);  ay += __shfl_xor(ay, 16, 64);
    ax += __shfl_xor(ax, 32, 64);  ay += __shfl_xor(ay, 32, 64);
    if (g == 0) {
        float sc = inr[r];
        float2 b3v = ((const float2*)b3)[ch + f];
        float2 bsv = ((const float2*)bs)[ch + f];
        float2 sk = ((const float2*)(Pskip + (size_t)r * 64))[ch + f];
        float2 o;
        o.x = 0.6f * (sk.x + bsv.x) + 0.4f * (sc * ax + b3v.x);
        o.y = 0.6f * (sk.y + bsv.y) + 0.4f * (sc * ay + b3v.y);
        __builtin_nontemporal_store(o.x, out + (size_t)r * 64 + (ch + f) * 2);
        __builtin_nontemporal_store(o.y, out + (size_t)r * 64 + (ch + f) * 2 + 1);
    }
}

// ---------------- MFMA GEMM: A[N][128] fp16 @ W (via WT fp16), fp32 accum ----------------
// MODE0: h1 = relu(acc + b1); Cf=h1 (fp32), Chh=h1*onr (fp16)
// MODE1: h2 = relu(0.6*Hres + 0.4*(acc + b2)); Chh=h2 (fp16)
// MODE2: jt<4: Cf=acc (Pskip fp32 ld64); jt>=4: Chh=acc*onr (Ph fp16 ld64)
template <int MODE>
__global__ __launch_bounds__(TPB) void k_mgemm(const __half* __restrict__ Ah,
                                               const __half* __restrict__ WT,
                                               const float* __restrict__ bias,
                                               const float* __restrict__ Hres,
                                               const float* __restrict__ onr,
                                               float* __restrict__ Cf, __half* __restrict__ Chh,
                                               int N) {
    __shared__ _Float16 As[64][136];
    int t = threadIdx.x;
    int bm = blockIdx.x * 64;
#pragma unroll
    for (int rep = 0; rep < 4; ++rep) {
        int c = rep * TPB + t;
        int row = c >> 4, cc = c & 15;
        int grow = bm + row;
        f16x8 v = {0, 0, 0, 0, 0, 0, 0, 0};
        if (grow < N) v = *(const f16x8*)(Ah + (size_t)grow * 128 + cc * 8);
        *(f16x8*)(&As[row][cc * 8]) = v;
    }
    __syncthreads();
    int l = t & 63;
    int w = t >> 6;
    int wrow = w * 16;
    int lr = l & 15;
    int lk = (l >> 4) * 8;
    f32x4 acc[8];
    f32x4 zero = {0.f, 0.f, 0.f, 0.f};
#pragma unroll
    for (int j = 0; j < 8; ++j) acc[j] = zero;
#pragma unroll
    for (int kk = 0; kk < 4; ++kk) {
        f16x8 af = *(const f16x8*)(&As[wrow + lr][kk * 32 + lk]);
#pragma unroll
        for (int jt = 0; jt < 8; ++jt) {
            f16x8 bf = *(const f16x8*)(WT + (size_t)(jt * 16 + lr) * 128 + kk * 32 + lk);
            acc[jt] = __builtin_amdgcn_mfma_f32_16x16x32_f16(af, bf, acc[jt], 0, 0, 0);
        }
    }
    int r0 = (l >> 4) * 4;
    float onr4[4];
    if (MODE == 0 || MODE == 2) {
#pragma unroll
        for (int r = 0; r < 4; ++r) {
            int row = bm + wrow + r0 + r;
            onr4[r] = (row < N) ? onr[row] : 0.f;
        }
    }
#pragma unroll
    for (int jt = 0; jt < 8; ++jt) {
        int col = jt * 16 + lr;
        float bv = 0.f;
        if (MODE != 2) bv = bias[col];
#pragma unroll
        for (int r = 0; r < 4; ++r) {
            int row = bm + wrow + r0 + r;
            if (row >= N) continue;
            float v = acc[jt][r] + bv;
            if (MODE == 0) {
                v = fmaxf(v, 0.f);
                Cf[(size_t)row * 128 + col] = v;
                Chh[(size_t)row * 128 + col] = __float2half(v * onr4[r]);
            } else if (MODE == 1) {
                float h1 = Hres[(size_t)row * 128 + col];
                v = fmaxf(0.6f * h1 + 0.4f * v, 0.f);
                Chh[(size_t)row * 128 + col] = __float2half(v);
            } else {
                if (jt < 4) Cf[(size_t)row * 64 + col] = v;
                else        Chh[(size_t)row * 64 + (col - 64)] = __float2half(v * onr4[r]);
            }
        }
    }
}

extern "C" void kernel_launch(void* const* d_in, const int* in_sizes, int n_in,
                              void* d_out, int out_size, void* d_ws, size_t ws_size,
                              hipStream_t stream) {
    const float* x  = (const float*)d_in[0];
    const int*   ei = (const int*)d_in[1];
    const float* W1 = (const float*)d_in[2];
    const float* b1 = (const float*)d_in[3];
    const float* W2 = (const float*)d_in[4];
    const float* b2 = (const float*)d_in[5];
    const float* W3 = (const float*)d_in[6];
    const float* b3 = (const float*)d_in[7];
    const float* Ws = (const float*)d_in[8];
    const float* bs = (const float*)d_in[9];
    float* out = (float*)d_out;

    int N = in_sizes[0] / 128;
    int E = in_sizes[1] / 2;

    char* p = (char*)d_ws;
    auto alloc = [&](size_t bytes) -> char* {
        char* r = p;
        p += (bytes + 255) & ~(size_t)255;
        return r;
    };
    size_t npad = ((size_t)N * 4 + 255) & ~(size_t)255;
    int*   cnt  = (int*)alloc(npad);            // | contiguous -> single memset
    int*   od   = (int*)alloc(npad);            // |
    float* onr  = (float*)alloc((size_t)N * 4);
    float* inr  = (float*)alloc((size_t)N * 4);
    __half* W1T = (__half*)alloc(128 * 128 * 2);
    __half* W2T = (__half*)alloc(128 * 128 * 2);
    __half* WCT = (__half*)alloc(128 * 128 * 2);
    unsigned short* slots = (unsigned short*)alloc((size_t)N * CAP * 2);   // 6.4 MB
    __half* xh   = (__half*)alloc((size_t)N * 128 * 2);  // 12.8 MB; Pskip aliases after layer 0
    __half* aggh = (__half*)alloc((size_t)N * 128 * 2);  // 12.8 MB; Ph aliases after mgemm<1>
    float*  h1s  = (float*)alloc((size_t)N * 128 * 4);   // 25.6 MB fp32 h1 (residual)
    __half* h1h  = (__half*)alloc((size_t)N * 128 * 2);  // 12.8 MB h1*onr; h2h aliases after L1 spmm
    (void)ws_size; (void)n_in; (void)out_size;

    float*  Pskip = (float*)xh;      // xh dead after L0 spmm passes
    __half* Ph    = (__half*)aggh;   // aggh dead after mgemm<1>
    __half* h2h   = h1h;             // h1h dead after L1 spmm passes

    int cBlocks = ((E + 3) / 4 + TPB - 1) / TPB;
    int nBlocks = (N + TPB - 1) / TPB;
    int cvtBlocks = (N * 32 + TPB - 1) / TPB;
    int spmmBlocks = (N + 3) / 4;
    int mgemmBlocks = (N + 63) / 64;

    hipMemsetAsync(cnt, 0, npad * 2, stream);   // cnt + od

    k_count<<<cBlocks, TPB, 0, stream>>>(ei, E, cnt, od, slots);
    k_norm<<<nBlocks, TPB, 0, stream>>>(od, cnt, onr, inr, N);
    k_cvtw<<<192, TPB, 0, stream>>>(W1, W2, Ws, W3, W1T, W2T, WCT);
    k_cvt<<<cvtBlocks, TPB, 0, stream>>>(x, onr, (__half2*)xh, N * 32);

    // layer 0: aggh = inr .* sum(xh[s]) — 4 L2-resident feature-chunk passes
    for (int c = 0; c < 4; ++c)
        k_spmmc<<<spmmBlocks, TPB, 0, stream>>>((const __half2*)xh, cnt, slots, inr,
                                                (__half2*)aggh, N, c * 16);
    k_mgemm<0><<<mgemmBlocks, TPB, 0, stream>>>(aggh, W1T, b1, nullptr, onr, h1s, h1h, N);
    // layer 1: aggh = inr .* sum(h1h[s])
    for (int c = 0; c < 4; ++c)
        k_spmmc<<<spmmBlocks, TPB, 0, stream>>>((const __half2*)h1h, cnt, slots, inr,
                                                (__half2*)aggh, N, c * 16);
    k_mgemm<1><<<mgemmBlocks, TPB, 0, stream>>>(aggh, W2T, b2, h1s, onr, nullptr, h2h, N);
    // layer 2: Pskip = h2@Ws (fp32); Ph = onr .* (h2@W3) (fp16)
    k_mgemm<2><<<mgemmBlocks, TPB, 0, stream>>>(h2h, WCT, nullptr, nullptr, onr, Pskip, Ph, N);
    // out = 0.6*(Pskip+bs) + 0.4*(inr .* gather(Ph) + b3) — 2 chunk passes
    for (int c = 0; c < 2; ++c)
        k_finalc<<<spmmBlocks, TPB, 0, stream>>>(Pskip, (const __half2*)Ph, cnt, slots, inr,
                                                 b3, bs, out, N, c * 16);
}

// Round 11
// 429.275 us; speedup vs baseline: 1.3889x; 1.3889x over previous
//
#include <hip/hip_runtime.h>
#include <hip/hip_fp16.h>
#include <math.h>

#define TPB 256
#define CAP 64   // ELL row capacity; in-deg ~ Poisson(16); P(deg>=64) ~ 1e-20; clamped anyway.

typedef _Float16 f16x8 __attribute__((ext_vector_type(8)));
typedef float f32x4 __attribute__((ext_vector_type(4)));

// ---------------- fused count + ELL fill, 4 edges/thread ----------------
// Atomic-throughput-bound at ~22 G atomics/s (measured r4-r10); algorithmic ceiling.
__global__ __launch_bounds__(TPB) void k_count(const int* __restrict__ ei, int E,
                                               int* __restrict__ cnt, int* __restrict__ od,
                                               unsigned short* __restrict__ slots) {
    int t = blockIdx.x * TPB + threadIdx.x;
    int base = t * 4;
    if (base + 3 < E) {
        int4 s4 = *(const int4*)(ei + base);
        int4 d4 = *(const int4*)(ei + E + base);
        int p0 = atomicAdd(&cnt[d4.x], 1);
        int p1 = atomicAdd(&cnt[d4.y], 1);
        int p2 = atomicAdd(&cnt[d4.z], 1);
        int p3 = atomicAdd(&cnt[d4.w], 1);
        atomicAdd(&od[s4.x], 1);
        atomicAdd(&od[s4.y], 1);
        atomicAdd(&od[s4.z], 1);
        atomicAdd(&od[s4.w], 1);
        if (p0 < CAP) slots[(d4.x << 6) + p0] = (unsigned short)s4.x;
        if (p1 < CAP) slots[(d4.y << 6) + p1] = (unsigned short)s4.y;
        if (p2 < CAP) slots[(d4.z << 6) + p2] = (unsigned short)s4.z;
        if (p3 < CAP) slots[(d4.w << 6) + p3] = (unsigned short)s4.w;
    } else {
        for (int e = base; e < E; ++e) {
            int s = ei[e], d = ei[E + e];
            int pos = atomicAdd(&cnt[d], 1);
            if (pos < CAP) slots[(d << 6) + pos] = (unsigned short)s;
            atomicAdd(&od[s], 1);
        }
    }
}

// ---------------- norms ----------------
__global__ __launch_bounds__(TPB) void k_norm(const int* __restrict__ od, const int* __restrict__ cnt,
                                              float* __restrict__ onr, float* __restrict__ inr, int N) {
    int i = blockIdx.x * TPB + threadIdx.x;
    if (i < N) {
        onr[i] = 1.0f / sqrtf(fmaxf((float)od[i], 1.0f));
        inr[i] = 1.0f / sqrtf(fmaxf((float)cnt[i], 1.0f));
    }
}

// ---------------- transpose+convert weights to fp16 WT[j][k] = W[k][j] ----------------
__global__ __launch_bounds__(TPB) void k_cvtw(const float* __restrict__ W1, const float* __restrict__ W2,
                                              const float* __restrict__ Ws, const float* __restrict__ W3,
                                              __half* __restrict__ W1T, __half* __restrict__ W2T,
                                              __half* __restrict__ WCT) {
    int idx = blockIdx.x * TPB + threadIdx.x;   // 0 .. 3*16384-1
    int m = idx >> 14;
    int r = idx & 16383;
    int j = r >> 7, k = r & 127;
    float v;
    __half* dst;
    if (m == 0)      { v = W1[k * 128 + j]; dst = W1T; }
    else if (m == 1) { v = W2[k * 128 + j]; dst = W2T; }
    else             { v = (j < 64) ? Ws[k * 64 + j] : W3[k * 64 + (j - 64)]; dst = WCT; }
    dst[r] = __float2half(v);
}

// ---------------- convert x -> fp16, prescaled by onr[row] ----------------
__global__ __launch_bounds__(TPB) void k_cvt(const float* __restrict__ x, const float* __restrict__ onr,
                                             __half2* __restrict__ xh, int nF4) {  // nF4 = N*32
    int i4 = blockIdx.x * TPB + threadIdx.x;
    if (i4 >= nF4) return;
    int row = i4 >> 5;
    float on = onr[row];
    float4 v = ((const float4*)x)[i4];
    __half2 a = __floats2half2_rn(v.x * on, v.y * on);
    __half2 b = __floats2half2_rn(v.z * on, v.w * on);
    uint2 u;
    u.x = *reinterpret_cast<unsigned int*>(&a);
    u.y = *reinterpret_cast<unsigned int*>(&b);
    ((uint2*)xh)[i4] = u;
}

// ---------------- chunked SpMM, MLP-preserving: 16-lane group owns ONE row ----------------
// 32-feat slice (3.2 MB of table lines < 4 MB per-XCD L2). 4 rows/wave, 16 rows/block.
// Each group iterates its own row's edges 8-deep (8 gathers in flight), lane owns 1 half2 feat.
// Slots via nontemporal uint loads; agg store nontemporal (protect resident slice).
__global__ __launch_bounds__(TPB) void k_spmmc(const __half2* __restrict__ hp,
                                               const int* __restrict__ cnt,
                                               const unsigned short* __restrict__ slots,
                                               const float* __restrict__ inr,
                                               __half2* __restrict__ aggh, int N, int cb) {
    int l = threadIdx.x & 63;
    int w = threadIdx.x >> 6;
    int g = l >> 4;           // row within wave
    int f = l & 15;           // half2 feat within chunk
    int r = blockIdx.x * 16 + w * 4 + g;
    if (r >= N) return;
    int n = cnt[r]; if (n > CAP) n = CAP;
    const unsigned int* slu = (const unsigned int*)(slots + (r << 6));
    const __half2* base = hp + cb + f;
    float ax0 = 0.f, ay0 = 0.f, ax1 = 0.f, ay1 = 0.f;
    int e = 0;
    for (; e + 7 < n; e += 8) {
        unsigned int q0 = __builtin_nontemporal_load(slu + (e >> 1));
        unsigned int q1 = __builtin_nontemporal_load(slu + (e >> 1) + 1);
        unsigned int q2 = __builtin_nontemporal_load(slu + (e >> 1) + 2);
        unsigned int q3 = __builtin_nontemporal_load(slu + (e >> 1) + 3);
        float2 f0 = __half22float2(base[(size_t)(q0 & 0xFFFF) * 64]);
        float2 f1 = __half22float2(base[(size_t)(q0 >> 16) * 64]);
        float2 f2 = __half22float2(base[(size_t)(q1 & 0xFFFF) * 64]);
        float2 f3 = __half22float2(base[(size_t)(q1 >> 16) * 64]);
        float2 f4 = __half22float2(base[(size_t)(q2 & 0xFFFF) * 64]);
        float2 f5 = __half22float2(base[(size_t)(q2 >> 16) * 64]);
        float2 f6 = __half22float2(base[(size_t)(q3 & 0xFFFF) * 64]);
        float2 f7 = __half22float2(base[(size_t)(q3 >> 16) * 64]);
        ax0 += f0.x + f1.x;  ay0 += f0.y + f1.y;
        ax1 += f2.x + f3.x;  ay1 += f2.y + f3.y;
        ax0 += f4.x + f5.x;  ay0 += f4.y + f5.y;
        ax1 += f6.x + f7.x;  ay1 += f6.y + f7.y;
    }
    for (; e + 1 < n; e += 2) {
        unsigned int q0 = __builtin_nontemporal_load(slu + (e >> 1));
        float2 f0 = __half22float2(base[(size_t)(q0 & 0xFFFF) * 64]);
        float2 f1 = __half22float2(base[(size_t)(q0 >> 16) * 64]);
        ax0 += f0.x + f1.x;  ay0 += f0.y + f1.y;
    }
    if (e < n) {
        float2 f0 = __half22float2(base[(size_t)slots[(r << 6) + e] * 64]);
        ax0 += f0.x;  ay0 += f0.y;
    }
    float sc = inr[r];
    __half2 o = __floats2half2_rn(sc * (ax0 + ax1), sc * (ay0 + ay1));
    unsigned int u = *reinterpret_cast<unsigned int*>(&o);
    __builtin_nontemporal_store(u, (unsigned int*)(aggh + (size_t)r * 64 + cb + f));
}

// ---------------- chunked final: same row-group structure over Ph (stride 32 half2) ----------------
__global__ __launch_bounds__(TPB) void k_finalc(const float* __restrict__ Pskip,
                                                const __half2* __restrict__ php,
                                                const int* __restrict__ cnt,
                                                const unsigned short* __restrict__ slots,
                                                const float* __restrict__ inr,
                                                const float* __restrict__ b3, const float* __restrict__ bs,
                                                float* __restrict__ out, int N, int ch) {
    int l = threadIdx.x & 63;
    int w = threadIdx.x >> 6;
    int g = l >> 4;
    int f = l & 15;
    int r = blockIdx.x * 16 + w * 4 + g;
    if (r >= N) return;
    int n = cnt[r]; if (n > CAP) n = CAP;
    const unsigned int* slu = (const unsigned int*)(slots + (r << 6));
    const __half2* base = php + ch + f;
    float ax0 = 0.f, ay0 = 0.f, ax1 = 0.f, ay1 = 0.f;
    int e = 0;
    for (; e + 7 < n; e += 8) {
        unsigned int q0 = __builtin_nontemporal_load(slu + (e >> 1));
        unsigned int q1 = __builtin_nontemporal_load(slu + (e >> 1) + 1);
        unsigned int q2 = __builtin_nontemporal_load(slu + (e >> 1) + 2);
        unsigned int q3 = __builtin_nontemporal_load(slu + (e >> 1) + 3);
        float2 f0 = __half22float2(base[(size_t)(q0 & 0xFFFF) * 32]);
        float2 f1 = __half22float2(base[(size_t)(q0 >> 16) * 32]);
        float2 f2 = __half22float2(base[(size_t)(q1 & 0xFFFF) * 32]);
        float2 f3 = __half22float2(base[(size_t)(q1 >> 16) * 32]);
        float2 f4 = __half22float2(base[(size_t)(q2 & 0xFFFF) * 32]);
        float2 f5 = __half22float2(base[(size_t)(q2 >> 16) * 32]);
        float2 f6 = __half22float2(base[(size_t)(q3 & 0xFFFF) * 32]);
        float2 f7 = __half22float2(base[(size_t)(q3 >> 16) * 32]);
        ax0 += f0.x + f1.x;  ay0 += f0.y + f1.y;
        ax1 += f2.x + f3.x;  ay1 += f2.y + f3.y;
        ax0 += f4.x + f5.x;  ay0 += f4.y + f5.y;
        ax1 += f6.x + f7.x;  ay1 += f6.y + f7.y;
    }
    for (; e + 1 < n; e += 2) {
        unsigned int q0 = __builtin_nontemporal_load(slu + (e >> 1));
        float2 f0 = __half22float2(base[(size_t)(q0 & 0xFFFF) * 32]);
        float2 f1 = __half22float2(base[(size_t)(q0 >> 16) * 32]);
        ax0 += f0.x + f1.x;  ay0 += f0.y + f1.y;
    }
    if (e < n) {
        float2 f0 = __half22float2(base[(size_t)slots[(r << 6) + e] * 32]);
        ax0 += f0.x;  ay0 += f0.y;
    }
    float sc = inr[r];
    float2 b3v = ((const float2*)b3)[ch + f];
    float2 bsv = ((const float2*)bs)[ch + f];
    float2 sk = ((const float2*)(Pskip + (size_t)r * 64))[ch + f];
    float2 o;
    o.x = 0.6f * (sk.x + bsv.x) + 0.4f * (sc * (ax0 + ax1) + b3v.x);
    o.y = 0.6f * (sk.y + bsv.y) + 0.4f * (sc * (ay0 + ay1) + b3v.y);
    __builtin_nontemporal_store(o.x, out + (size_t)r * 64 + (ch + f) * 2);
    __builtin_nontemporal_store(o.y, out + (size_t)r * 64 + (ch + f) * 2 + 1);
}

// ---------------- MFMA GEMM: A[N][128] fp16 @ W (via WT fp16), fp32 accum ----------------
// MODE0: h1 = relu(acc + b1); Cf=h1 (fp32), Chh=h1*onr (fp16)
// MODE1: h2 = relu(0.6*Hres + 0.4*(acc + b2)); Chh=h2 (fp16)
// MODE2: jt<4: Cf=acc (Pskip fp32 ld64); jt>=4: Chh=acc*onr (Ph fp16 ld64)
template <int MODE>
__global__ __launch_bounds__(TPB) void k_mgemm(const __half* __restrict__ Ah,
                                               const __half* __restrict__ WT,
                                               const float* __restrict__ bias,
                                               const float* __restrict__ Hres,
                                               const float* __restrict__ onr,
                                               float* __restrict__ Cf, __half* __restrict__ Chh,
                                               int N) {
    __shared__ _Float16 As[64][136];
    int t = threadIdx.x;
    int bm = blockIdx.x * 64;
#pragma unroll
    for (int rep = 0; rep < 4; ++rep) {
        int c = rep * TPB + t;
        int row = c >> 4, cc = c & 15;
        int grow = bm + row;
        f16x8 v = {0, 0, 0, 0, 0, 0, 0, 0};
        if (grow < N) v = *(const f16x8*)(Ah + (size_t)grow * 128 + cc * 8);
        *(f16x8*)(&As[row][cc * 8]) = v;
    }
    __syncthreads();
    int l = t & 63;
    int w = t >> 6;
    int wrow = w * 16;
    int lr = l & 15;
    int lk = (l >> 4) * 8;
    f32x4 acc[8];
    f32x4 zero = {0.f, 0.f, 0.f, 0.f};
#pragma unroll
    for (int j = 0; j < 8; ++j) acc[j] = zero;
#pragma unroll
    for (int kk = 0; kk < 4; ++kk) {
        f16x8 af = *(const f16x8*)(&As[wrow + lr][kk * 32 + lk]);
#pragma unroll
        for (int jt = 0; jt < 8; ++jt) {
            f16x8 bf = *(const f16x8*)(WT + (size_t)(jt * 16 + lr) * 128 + kk * 32 + lk);
            acc[jt] = __builtin_amdgcn_mfma_f32_16x16x32_f16(af, bf, acc[jt], 0, 0, 0);
        }
    }
    int r0 = (l >> 4) * 4;
    float onr4[4];
    if (MODE == 0 || MODE == 2) {
#pragma unroll
        for (int r = 0; r < 4; ++r) {
            int row = bm + wrow + r0 + r;
            onr4[r] = (row < N) ? onr[row] : 0.f;
        }
    }
#pragma unroll
    for (int jt = 0; jt < 8; ++jt) {
        int col = jt * 16 + lr;
        float bv = 0.f;
        if (MODE != 2) bv = bias[col];
#pragma unroll
        for (int r = 0; r < 4; ++r) {
            int row = bm + wrow + r0 + r;
            if (row >= N) continue;
            float v = acc[jt][r] + bv;
            if (MODE == 0) {
                v = fmaxf(v, 0.f);
                Cf[(size_t)row * 128 + col] = v;
                Chh[(size_t)row * 128 + col] = __float2half(v * onr4[r]);
            } else if (MODE == 1) {
                float h1 = Hres[(size_t)row * 128 + col];
                v = fmaxf(0.6f * h1 + 0.4f * v, 0.f);
                Chh[(size_t)row * 128 + col] = __float2half(v);
            } else {
                if (jt < 4) Cf[(size_t)row * 64 + col] = v;
                else        Chh[(size_t)row * 64 + (col - 64)] = __float2half(v * onr4[r]);
            }
        }
    }
}

extern "C" void kernel_launch(void* const* d_in, const int* in_sizes, int n_in,
                              void* d_out, int out_size, void* d_ws, size_t ws_size,
                              hipStream_t stream) {
    const float* x  = (const float*)d_in[0];
    const int*   ei = (const int*)d_in[1];
    const float* W1 = (const float*)d_in[2];
    const float* b1 = (const float*)d_in[3];
    const float* W2 = (const float*)d_in[4];
    const float* b2 = (const float*)d_in[5];
    const float* W3 = (const float*)d_in[6];
    const float* b3 = (const float*)d_in[7];
    const float* Ws = (const float*)d_in[8];
    const float* bs = (const float*)d_in[9];
    float* out = (float*)d_out;

    int N = in_sizes[0] / 128;
    int E = in_sizes[1] / 2;

    char* p = (char*)d_ws;
    auto alloc = [&](size_t bytes) -> char* {
        char* r = p;
        p += (bytes + 255) & ~(size_t)255;
        return r;
    };
    size_t npad = ((size_t)N * 4 + 255) & ~(size_t)255;
    int*   cnt  = (int*)alloc(npad);            // | contiguous -> single memset
    int*   od   = (int*)alloc(npad);            // |
    float* onr  = (float*)alloc((size_t)N * 4);
    float* inr  = (float*)alloc((size_t)N * 4);
    __half* W1T = (__half*)alloc(128 * 128 * 2);
    __half* W2T = (__half*)alloc(128 * 128 * 2);
    __half* WCT = (__half*)alloc(128 * 128 * 2);
    unsigned short* slots = (unsigned short*)alloc((size_t)N * CAP * 2);   // 6.4 MB
    __half* xh   = (__half*)alloc((size_t)N * 128 * 2);  // 12.8 MB; Pskip aliases after layer 0
    __half* aggh = (__half*)alloc((size_t)N * 128 * 2);  // 12.8 MB; Ph aliases after mgemm<1>
    float*  h1s  = (float*)alloc((size_t)N * 128 * 4);   // 25.6 MB fp32 h1 (residual)
    __half* h1h  = (__half*)alloc((size_t)N * 128 * 2);  // 12.8 MB h1*onr; h2h aliases after L1 spmm
    (void)ws_size; (void)n_in; (void)out_size;

    float*  Pskip = (float*)xh;      // xh dead after L0 spmm passes
    __half* Ph    = (__half*)aggh;   // aggh dead after mgemm<1>
    __half* h2h   = h1h;             // h1h dead after L1 spmm passes

    int cBlocks = ((E + 3) / 4 + TPB - 1) / TPB;
    int nBlocks = (N + TPB - 1) / TPB;
    int cvtBlocks = (N * 32 + TPB - 1) / TPB;
    int chunkBlocks = (N + 15) / 16;
    int mgemmBlocks = (N + 63) / 64;

    hipMemsetAsync(cnt, 0, npad * 2, stream);   // cnt + od

    k_count<<<cBlocks, TPB, 0, stream>>>(ei, E, cnt, od, slots);
    k_norm<<<nBlocks, TPB, 0, stream>>>(od, cnt, onr, inr, N);
    k_cvtw<<<192, TPB, 0, stream>>>(W1, W2, Ws, W3, W1T, W2T, WCT);
    k_cvt<<<cvtBlocks, TPB, 0, stream>>>(x, onr, (__half2*)xh, N * 32);

    // layer 0: aggh = inr .* sum(xh[s]) — 4 L2-resident feature-chunk passes (MLP-preserving)
    for (int c = 0; c < 4; ++c)
        k_spmmc<<<chunkBlocks, TPB, 0, stream>>>((const __half2*)xh, cnt, slots, inr,
                                                 (__half2*)aggh, N, c * 16);
    k_mgemm<0><<<mgemmBlocks, TPB, 0, stream>>>(aggh, W1T, b1, nullptr, onr, h1s, h1h, N);
    // layer 1: aggh = inr .* sum(h1h[s])
    for (int c = 0; c < 4; ++c)
        k_spmmc<<<chunkBlocks, TPB, 0, stream>>>((const __half2*)h1h, cnt, slots, inr,
                                                 (__half2*)aggh, N, c * 16);
    k_mgemm<1><<<mgemmBlocks, TPB, 0, stream>>>(aggh, W2T, b2, h1s, onr, nullptr, h2h, N);
    // layer 2: Pskip = h2@Ws (fp32); Ph = onr .* (h2@W3) (fp16)
    k_mgemm<2><<<mgemmBlocks, TPB, 0, stream>>>(h2h, WCT, nullptr, nullptr, onr, Pskip, Ph, N);
    // out = 0.6*(Pskip+bs) + 0.4*(inr .* gather(Ph) + b3) — 2 chunk passes
    for (int c = 0; c < 2; ++c)
        k_finalc<<<chunkBlocks, TPB, 0, stream>>>(Pskip, (const __half2*)Ph, cnt, slots, inr,
                                                  b3, bs, out, N, c * 16);
}

// Round 12
// 338.578 us; speedup vs baseline: 1.7609x; 1.2679x over previous
//
#include <hip/hip_runtime.h>
#include <hip/hip_fp16.h>
#include <math.h>

#define TPB 256
#define CAP 64   // ELL row capacity; in-deg ~ Poisson(16); P(deg>=64) ~ 1e-20; clamped anyway.

typedef _Float16 f16x8 __attribute__((ext_vector_type(8)));
typedef float f32x4 __attribute__((ext_vector_type(4)));

// ---------------- fused count + ELL fill, 4 edges/thread ----------------
// Atomic-throughput-bound at ~22 G atomics/s (measured r4-r11); algorithmic ceiling.
__global__ __launch_bounds__(TPB) void k_count(const int* __restrict__ ei, int E,
                                               int* __restrict__ cnt, int* __restrict__ od,
                                               unsigned short* __restrict__ slots) {
    int t = blockIdx.x * TPB + threadIdx.x;
    int base = t * 4;
    if (base + 3 < E) {
        int4 s4 = *(const int4*)(ei + base);
        int4 d4 = *(const int4*)(ei + E + base);
        int p0 = atomicAdd(&cnt[d4.x], 1);
        int p1 = atomicAdd(&cnt[d4.y], 1);
        int p2 = atomicAdd(&cnt[d4.z], 1);
        int p3 = atomicAdd(&cnt[d4.w], 1);
        atomicAdd(&od[s4.x], 1);
        atomicAdd(&od[s4.y], 1);
        atomicAdd(&od[s4.z], 1);
        atomicAdd(&od[s4.w], 1);
        if (p0 < CAP) slots[(d4.x << 6) + p0] = (unsigned short)s4.x;
        if (p1 < CAP) slots[(d4.y << 6) + p1] = (unsigned short)s4.y;
        if (p2 < CAP) slots[(d4.z << 6) + p2] = (unsigned short)s4.z;
        if (p3 < CAP) slots[(d4.w << 6) + p3] = (unsigned short)s4.w;
    } else {
        for (int e = base; e < E; ++e) {
            int s = ei[e], d = ei[E + e];
            int pos = atomicAdd(&cnt[d], 1);
            if (pos < CAP) slots[(d << 6) + pos] = (unsigned short)s;
            atomicAdd(&od[s], 1);
        }
    }
}

// ---------------- norms ----------------
__global__ __launch_bounds__(TPB) void k_norm(const int* __restrict__ od, const int* __restrict__ cnt,
                                              float* __restrict__ onr, float* __restrict__ inr, int N) {
    int i = blockIdx.x * TPB + threadIdx.x;
    if (i < N) {
        onr[i] = 1.0f / sqrtf(fmaxf((float)od[i], 1.0f));
        inr[i] = 1.0f / sqrtf(fmaxf((float)cnt[i], 1.0f));
    }
}

// ---------------- transpose+convert weights to fp16 WT[j][k] = W[k][j] ----------------
__global__ __launch_bounds__(TPB) void k_cvtw(const float* __restrict__ W1, const float* __restrict__ W2,
                                              const float* __restrict__ Ws, const float* __restrict__ W3,
                                              __half* __restrict__ W1T, __half* __restrict__ W2T,
                                              __half* __restrict__ WCT) {
    int idx = blockIdx.x * TPB + threadIdx.x;   // 0 .. 3*16384-1
    int m = idx >> 14;
    int r = idx & 16383;
    int j = r >> 7, k = r & 127;
    float v;
    __half* dst;
    if (m == 0)      { v = W1[k * 128 + j]; dst = W1T; }
    else if (m == 1) { v = W2[k * 128 + j]; dst = W2T; }
    else             { v = (j < 64) ? Ws[k * 64 + j] : W3[k * 64 + (j - 64)]; dst = WCT; }
    dst[r] = __float2half(v);
}

// ---------------- per-row int8 quantize, 128-wide: q = rint(src*onr / scale), scale stored ----------------
// One wave per row; lane owns 2 feats; full-wave abs-max butterfly.
__global__ __launch_bounds__(TPB) void k_quant128(const float* __restrict__ src,
                                                  const float* __restrict__ onr,
                                                  char2* __restrict__ q, float* __restrict__ sc, int N) {
    int l = threadIdx.x & 63;
    int r = blockIdx.x * 4 + (threadIdx.x >> 6);
    if (r >= N) return;
    float on = onr[r];
    float2 v = ((const float2*)(src + (size_t)r * 128))[l];
    v.x *= on;  v.y *= on;
    float m = fmaxf(fabsf(v.x), fabsf(v.y));
#pragma unroll
    for (int d = 1; d < 64; d <<= 1) m = fmaxf(m, __shfl_xor(m, d, 64));
    float inv = (m > 1e-20f) ? 127.0f / m : 0.0f;
    char2 o;
    o.x = (signed char)(int)rintf(v.x * inv);
    o.y = (signed char)(int)rintf(v.y * inv);
    q[(size_t)r * 64 + l] = o;
    if (l == 0) sc[r] = m * (1.0f / 127.0f);
}

// ---------------- per-row int8 quantize, 64-wide fp16 input (Ph table) ----------------
// 2 rows/wave (32 lanes each), butterfly within 32-lane group.
__global__ __launch_bounds__(TPB) void k_quant64(const __half2* __restrict__ ph,
                                                 char2* __restrict__ q, float* __restrict__ sc, int N) {
    int t = threadIdx.x;
    int l = t & 63;
    int f = l & 31;
    int r = blockIdx.x * 8 + (t >> 6) * 2 + (l >> 5);
    if (r >= N) return;
    float2 v = __half22float2(ph[(size_t)r * 32 + f]);
    float m = fmaxf(fabsf(v.x), fabsf(v.y));
#pragma unroll
    for (int d = 1; d < 32; d <<= 1) m = fmaxf(m, __shfl_xor(m, d, 64));
    float inv = (m > 1e-20f) ? 127.0f / m : 0.0f;
    char2 o;
    o.x = (signed char)(int)rintf(v.x * inv);
    o.y = (signed char)(int)rintf(v.y * inv);
    q[(size_t)r * 32 + f] = o;
    if (f == 0) sc[r] = m * (1.0f / 127.0f);
}

// ---------------- SpMM over ELL, int8 table (128-wide = 2 lines/edge), fp32 accum ----------------
// One wave per dst row, 8-deep unroll (r9 structure). Per-edge scale from 200KB L2-resident array.
__global__ __launch_bounds__(TPB) void k_spmmq(const char2* __restrict__ qt,
                                               const float* __restrict__ sc,
                                               const int* __restrict__ cnt,
                                               const unsigned short* __restrict__ slots,
                                               const float* __restrict__ inr,
                                               __half2* __restrict__ aggh, int N) {
    int l = threadIdx.x & 63;
    int r = blockIdx.x * 4 + (threadIdx.x >> 6);
    if (r >= N) return;
    int n = cnt[r]; if (n > CAP) n = CAP;
    const unsigned short* sl = slots + (r << 6);
    const char2* base = qt + l;
    float ax0 = 0.f, ay0 = 0.f, ax1 = 0.f, ay1 = 0.f;
    float ax2 = 0.f, ay2 = 0.f, ax3 = 0.f, ay3 = 0.f;
    int e = 0;
    for (; e + 7 < n; e += 8) {
        ushort4 qa = *(const ushort4*)(sl + e);
        ushort4 qb = *(const ushort4*)(sl + e + 4);
        char2 v0 = base[(size_t)qa.x * 64];
        char2 v1 = base[(size_t)qa.y * 64];
        char2 v2 = base[(size_t)qa.z * 64];
        char2 v3 = base[(size_t)qa.w * 64];
        char2 v4 = base[(size_t)qb.x * 64];
        char2 v5 = base[(size_t)qb.y * 64];
        char2 v6 = base[(size_t)qb.z * 64];
        char2 v7 = base[(size_t)qb.w * 64];
        float s0 = sc[qa.x], s1 = sc[qa.y], s2 = sc[qa.z], s3 = sc[qa.w];
        float s4 = sc[qb.x], s5 = sc[qb.y], s6 = sc[qb.z], s7 = sc[qb.w];
        ax0 += s0 * (float)v0.x + s1 * (float)v1.x;  ay0 += s0 * (float)v0.y + s1 * (float)v1.y;
        ax1 += s2 * (float)v2.x + s3 * (float)v3.x;  ay1 += s2 * (float)v2.y + s3 * (float)v3.y;
        ax2 += s4 * (float)v4.x + s5 * (float)v5.x;  ay2 += s4 * (float)v4.y + s5 * (float)v5.y;
        ax3 += s6 * (float)v6.x + s7 * (float)v7.x;  ay3 += s6 * (float)v6.y + s7 * (float)v7.y;
    }
    for (; e + 3 < n; e += 4) {
        ushort4 qa = *(const ushort4*)(sl + e);
        char2 v0 = base[(size_t)qa.x * 64];
        char2 v1 = base[(size_t)qa.y * 64];
        char2 v2 = base[(size_t)qa.z * 64];
        char2 v3 = base[(size_t)qa.w * 64];
        float s0 = sc[qa.x], s1 = sc[qa.y], s2 = sc[qa.z], s3 = sc[qa.w];
        ax0 += s0 * (float)v0.x + s1 * (float)v1.x;  ay0 += s0 * (float)v0.y + s1 * (float)v1.y;
        ax1 += s2 * (float)v2.x + s3 * (float)v3.x;  ay1 += s2 * (float)v2.y + s3 * (float)v3.y;
    }
    for (; e < n; ++e) {
        int s = sl[e];
        char2 v0 = base[(size_t)s * 64];
        float s0 = sc[s];
        ax0 += s0 * (float)v0.x;  ay0 += s0 * (float)v0.y;
    }
    float scl = inr[r];
    aggh[(size_t)r * 64 + l] =
        __floats2half2_rn(scl * ((ax0 + ax1) + (ax2 + ax3)), scl * ((ay0 + ay1) + (ay2 + ay3)));
}

// ---------------- final: gather int8 Ph (64-wide = 1 line/edge) + blend with Pskip ----------------
// 2 rows per wave (32 lanes each, lane owns 2 out feats), 8-deep unroll, no shuffles.
__global__ __launch_bounds__(TPB) void k_finalq(const float* __restrict__ Pskip,
                                                const char2* __restrict__ pq,
                                                const float* __restrict__ psc,
                                                const int* __restrict__ cnt,
                                                const unsigned short* __restrict__ slots,
                                                const float* __restrict__ inr,
                                                const float* __restrict__ b3, const float* __restrict__ bs,
                                                float* __restrict__ out, int N) {
    int t = threadIdx.x;
    int l = t & 63;
    int f = l & 31;
    int r = blockIdx.x * 8 + (t >> 6) * 2 + (l >> 5);
    if (r >= N) return;
    int n = cnt[r]; if (n > CAP) n = CAP;
    const unsigned short* sl = slots + (r << 6);
    const char2* base = pq + f;
    float ax0 = 0.f, ay0 = 0.f, ax1 = 0.f, ay1 = 0.f;
    int e = 0;
    for (; e + 7 < n; e += 8) {
        ushort4 qa = *(const ushort4*)(sl + e);
        ushort4 qb = *(const ushort4*)(sl + e + 4);
        char2 v0 = base[(size_t)qa.x * 32];
        char2 v1 = base[(size_t)qa.y * 32];
        char2 v2 = base[(size_t)qa.z * 32];
        char2 v3 = base[(size_t)qa.w * 32];
        char2 v4 = base[(size_t)qb.x * 32];
        char2 v5 = base[(size_t)qb.y * 32];
        char2 v6 = base[(size_t)qb.z * 32];
        char2 v7 = base[(size_t)qb.w * 32];
        float s0 = psc[qa.x], s1 = psc[qa.y], s2 = psc[qa.z], s3 = psc[qa.w];
        float s4 = psc[qb.x], s5 = psc[qb.y], s6 = psc[qb.z], s7 = psc[qb.w];
        ax0 += s0 * (float)v0.x + s1 * (float)v1.x;  ay0 += s0 * (float)v0.y + s1 * (float)v1.y;
        ax1 += s2 * (float)v2.x + s3 * (float)v3.x;  ay1 += s2 * (float)v2.y + s3 * (float)v3.y;
        ax0 += s4 * (float)v4.x + s5 * (float)v5.x;  ay0 += s4 * (float)v4.y + s5 * (float)v5.y;
        ax1 += s6 * (float)v6.x + s7 * (float)v7.x;  ay1 += s6 * (float)v6.y + s7 * (float)v7.y;
    }
    for (; e + 3 < n; e += 4) {
        ushort4 qa = *(const ushort4*)(sl + e);
        char2 v0 = base[(size_t)qa.x * 32];
        char2 v1 = base[(size_t)qa.y * 32];
        char2 v2 = base[(size_t)qa.z * 32];
        char2 v3 = base[(size_t)qa.w * 32];
        float s0 = psc[qa.x], s1 = psc[qa.y], s2 = psc[qa.z], s3 = psc[qa.w];
        ax0 += s0 * (float)v0.x + s1 * (float)v1.x;  ay0 += s0 * (float)v0.y + s1 * (float)v1.y;
        ax1 += s2 * (float)v2.x + s3 * (float)v3.x;  ay1 += s2 * (float)v2.y + s3 * (float)v3.y;
    }
    for (; e < n; ++e) {
        int s = sl[e];
        char2 v0 = base[(size_t)s * 32];
        float s0 = psc[s];
        ax0 += s0 * (float)v0.x;  ay0 += s0 * (float)v0.y;
    }
    float scl = inr[r];
    float2 b3v = ((const float2*)b3)[f];
    float2 bsv = ((const float2*)bs)[f];
    float2 sk = ((const float2*)(Pskip + (size_t)r * 64))[f];
    float gx = scl * (ax0 + ax1) + b3v.x;
    float gy = scl * (ay0 + ay1) + b3v.y;
    float2 o;
    o.x = 0.6f * (sk.x + bsv.x) + 0.4f * gx;
    o.y = 0.6f * (sk.y + bsv.y) + 0.4f * gy;
    ((float2*)(out + (size_t)r * 64))[f] = o;
}

// ---------------- MFMA GEMM: A[N][128] fp16 @ W (via WT fp16), fp32 accum ----------------
// MODE0: h1 = relu(acc + b1) -> Cf fp32 only
// MODE1: h2 = relu(0.6*Hres + 0.4*(acc + b2)) -> Chh fp16
// MODE2: jt<4: Cf=acc (Pskip fp32 ld64); jt>=4: Chh=acc*onr (Ph fp16 ld64)
template <int MODE>
__global__ __launch_bounds__(TPB) void k_mgemm(const __half* __restrict__ Ah,
                                               const __half* __restrict__ WT,
                                               const float* __restrict__ bias,
                                               const float* __restrict__ Hres,
                                               const float* __restrict__ onr,
                                               float* __restrict__ Cf, __half* __restrict__ Chh,
                                               int N) {
    __shared__ _Float16 As[64][136];
    int t = threadIdx.x;
    int bm = blockIdx.x * 64;
#pragma unroll
    for (int rep = 0; rep < 4; ++rep) {
        int c = rep * TPB + t;
        int row = c >> 4, cc = c & 15;
        int grow = bm + row;
        f16x8 v = {0, 0, 0, 0, 0, 0, 0, 0};
        if (grow < N) v = *(const f16x8*)(Ah + (size_t)grow * 128 + cc * 8);
        *(f16x8*)(&As[row][cc * 8]) = v;
    }
    __syncthreads();
    int l = t & 63;
    int w = t >> 6;
    int wrow = w * 16;
    int lr = l & 15;
    int lk = (l >> 4) * 8;
    f32x4 acc[8];
    f32x4 zero = {0.f, 0.f, 0.f, 0.f};
#pragma unroll
    for (int j = 0; j < 8; ++j) acc[j] = zero;
#pragma unroll
    for (int kk = 0; kk < 4; ++kk) {
        f16x8 af = *(const f16x8*)(&As[wrow + lr][kk * 32 + lk]);
#pragma unroll
        for (int jt = 0; jt < 8; ++jt) {
            f16x8 bf = *(const f16x8*)(WT + (size_t)(jt * 16 + lr) * 128 + kk * 32 + lk);
            acc[jt] = __builtin_amdgcn_mfma_f32_16x16x32_f16(af, bf, acc[jt], 0, 0, 0);
        }
    }
    int r0 = (l >> 4) * 4;
    float onr4[4];
    if (MODE == 2) {
#pragma unroll
        for (int r = 0; r < 4; ++r) {
            int row = bm + wrow + r0 + r;
            onr4[r] = (row < N) ? onr[row] : 0.f;
        }
    }
#pragma unroll
    for (int jt = 0; jt < 8; ++jt) {
        int col = jt * 16 + lr;
        float bv = 0.f;
        if (MODE != 2) bv = bias[col];
#pragma unroll
        for (int r = 0; r < 4; ++r) {
            int row = bm + wrow + r0 + r;
            if (row >= N) continue;
            float v = acc[jt][r] + bv;
            if (MODE == 0) {
                v = fmaxf(v, 0.f);
                Cf[(size_t)row * 128 + col] = v;
            } else if (MODE == 1) {
                float h1 = Hres[(size_t)row * 128 + col];
                v = fmaxf(0.6f * h1 + 0.4f * v, 0.f);
                Chh[(size_t)row * 128 + col] = __float2half(v);
            } else {
                if (jt < 4) Cf[(size_t)row * 64 + col] = v;
                else        Chh[(size_t)row * 64 + (col - 64)] = __float2half(v * onr4[r]);
            }
        }
    }
}

extern "C" void kernel_launch(void* const* d_in, const int* in_sizes, int n_in,
                              void* d_out, int out_size, void* d_ws, size_t ws_size,
                              hipStream_t stream) {
    const float* x  = (const float*)d_in[0];
    const int*   ei = (const int*)d_in[1];
    const float* W1 = (const float*)d_in[2];
    const float* b1 = (const float*)d_in[3];
    const float* W2 = (const float*)d_in[4];
    const float* b2 = (const float*)d_in[5];
    const float* W3 = (const float*)d_in[6];
    const float* b3 = (const float*)d_in[7];
    const float* Ws = (const float*)d_in[8];
    const float* bs = (const float*)d_in[9];
    float* out = (float*)d_out;

    int N = in_sizes[0] / 128;
    int E = in_sizes[1] / 2;

    char* p = (char*)d_ws;
    auto alloc = [&](size_t bytes) -> char* {
        char* r = p;
        p += (bytes + 255) & ~(size_t)255;
        return r;
    };
    size_t npad = ((size_t)N * 4 + 255) & ~(size_t)255;
    int*   cnt  = (int*)alloc(npad);            // | contiguous -> single memset
    int*   od   = (int*)alloc(npad);            // |
    float* onr  = (float*)alloc((size_t)N * 4);
    float* inr  = (float*)alloc((size_t)N * 4);
    __half* W1T = (__half*)alloc(128 * 128 * 2);
    __half* W2T = (__half*)alloc(128 * 128 * 2);
    __half* WCT = (__half*)alloc(128 * 128 * 2);
    unsigned short* slots = (unsigned short*)alloc((size_t)N * CAP * 2);   // 6.4 MB
    char2* xq   = (char2*)alloc((size_t)N * 64 * 2);     // 6.4 MB; Ph aliases after L0 spmm
    float* xsc  = (float*)alloc((size_t)N * 4);
    __half* aggh = (__half*)alloc((size_t)N * 128 * 2);  // 12.8 MB; Pskip aliases after mgemm<1>
    float*  h1s  = (float*)alloc((size_t)N * 128 * 4);   // 25.6 MB fp32 h1 (residual)
    char2* h1q  = (char2*)alloc((size_t)N * 64 * 2);     // 6.4 MB; pq aliases after L1 spmm
    float* h1sc = (float*)alloc((size_t)N * 4);          // psc aliases
    __half* h2h  = (__half*)alloc((size_t)N * 128 * 2);  // 12.8 MB
    (void)ws_size; (void)n_in; (void)out_size;           // total ~72 MB

    float*  Pskip = (float*)aggh;    // aggh dead after mgemm<1>; N*64*4 = 12.8 MB fits
    __half* Ph    = (__half*)xq;     // xq dead after L0 spmm; N*64*2 = 6.4 MB fits
    char2*  pq    = h1q;             // h1q dead after L1 spmm; N*32*2 = 3.2 MB fits
    float*  psc   = h1sc;            // h1sc dead after L1 spmm

    int cBlocks = ((E + 3) / 4 + TPB - 1) / TPB;
    int nBlocks = (N + TPB - 1) / TPB;
    int spmmBlocks = (N + 3) / 4;
    int half8Blocks = (N + 7) / 8;
    int mgemmBlocks = (N + 63) / 64;

    hipMemsetAsync(cnt, 0, npad * 2, stream);   // cnt + od

    k_count<<<cBlocks, TPB, 0, stream>>>(ei, E, cnt, od, slots);
    k_norm<<<nBlocks, TPB, 0, stream>>>(od, cnt, onr, inr, N);
    k_cvtw<<<192, TPB, 0, stream>>>(W1, W2, Ws, W3, W1T, W2T, WCT);

    // layer 0: xq = int8(x*onr) ; aggh = inr .* gather-sum(xq) ; h1s = relu(aggh@W1+b1)
    k_quant128<<<spmmBlocks, TPB, 0, stream>>>(x, onr, xq, xsc, N);
    k_spmmq<<<spmmBlocks, TPB, 0, stream>>>(xq, xsc, cnt, slots, inr, (__half2*)aggh, N);
    k_mgemm<0><<<mgemmBlocks, TPB, 0, stream>>>(aggh, W1T, b1, nullptr, onr, h1s, nullptr, N);
    // layer 1: h1q = int8(h1*onr) ; aggh = inr .* gather-sum(h1q) ; h2h = relu(0.6*h1+0.4*(aggh@W2+b2))
    k_quant128<<<spmmBlocks, TPB, 0, stream>>>(h1s, onr, h1q, h1sc, N);
    k_spmmq<<<spmmBlocks, TPB, 0, stream>>>(h1q, h1sc, cnt, slots, inr, (__half2*)aggh, N);
    k_mgemm<1><<<mgemmBlocks, TPB, 0, stream>>>(aggh, W2T, b2, h1s, onr, nullptr, h2h, N);
    // layer 2: Pskip = h2@Ws (fp32); Ph = onr .* (h2@W3) (fp16) ; pq = int8(Ph)
    k_mgemm<2><<<mgemmBlocks, TPB, 0, stream>>>(h2h, WCT, nullptr, nullptr, onr, Pskip, Ph, N);
    k_quant64<<<half8Blocks, TPB, 0, stream>>>((const __half2*)Ph, pq, psc, N);
    // out = 0.6*(Pskip+bs) + 0.4*(inr .* gather(pq) + b3)
    k_finalq<<<half8Blocks, TPB, 0, stream>>>(Pskip, pq, psc, cnt, slots, inr, b3, bs, out, N);
}